// Round 1
// baseline (262.826 us; speedup 1.0000x reference)
//
#include <hip/hip_runtime.h>
#include <math.h>

#define BB  256
#define TCC 256
#define DD  2048

typedef float4 f4;

// ---------------------------------------------------------------------------
// Kernel A: hw = h_dec @ W  (f32), split-K into 4 partials stored in d_ws.
// grid (32 e-tiles, 4 b-tiles, 4 k-splits), 256 threads.
// Tile: 64e x 64b, micro-tile 4e x 4b per thread, K-slice 512, Dc = 32.
// ---------------------------------------------------------------------------
__global__ __launch_bounds__(256) void hw_gemm_partial(
    const float* __restrict__ h,     // [B][D]
    const float* __restrict__ W,     // [D][D]
    float* __restrict__ part)        // [4][B][D]
{
    __shared__ float hs[32][68];     // [d][b] transposed, pad 68 (16B-aligned rows)
    __shared__ float wsm[32][64];    // [d][e]

    const int tid = threadIdx.x;
    const int e0 = blockIdx.x * 64;
    const int b0 = blockIdx.y * 64;
    const int z  = blockIdx.z;

    float acc[4][4];
    #pragma unroll
    for (int i = 0; i < 4; i++)
        #pragma unroll
        for (int j = 0; j < 4; j++) acc[i][j] = 0.f;

    const int ie = tid & 15;         // e micro index
    const int ib = tid >> 4;         // b micro index

    const int hr = tid >> 2;         // 0..63 : b row for h staging
    const int hc = (tid & 3) * 8;    // d offset for h staging
    const int wr = tid >> 3;         // 0..31 : d row for W staging
    const int wc = (tid & 7) * 8;    // e offset for W staging

    for (int d0 = z * 512; d0 < z * 512 + 512; d0 += 32) {
        // stage h transposed: hs[d][b]
        f4 ha = *(const f4*)&h[(size_t)(b0 + hr) * DD + d0 + hc];
        f4 hb = *(const f4*)&h[(size_t)(b0 + hr) * DD + d0 + hc + 4];
        hs[hc + 0][hr] = ha.x; hs[hc + 1][hr] = ha.y;
        hs[hc + 2][hr] = ha.z; hs[hc + 3][hr] = ha.w;
        hs[hc + 4][hr] = hb.x; hs[hc + 5][hr] = hb.y;
        hs[hc + 6][hr] = hb.z; hs[hc + 7][hr] = hb.w;
        // stage W: wsm[d][e]
        f4 wa = *(const f4*)&W[(size_t)(d0 + wr) * DD + e0 + wc];
        f4 wb = *(const f4*)&W[(size_t)(d0 + wr) * DD + e0 + wc + 4];
        *(f4*)&wsm[wr][wc]     = wa;
        *(f4*)&wsm[wr][wc + 4] = wb;
        __syncthreads();

        #pragma unroll
        for (int dd = 0; dd < 32; dd++) {
            f4 hv = *(const f4*)&hs[dd][ib * 4];
            f4 wv = *(const f4*)&wsm[dd][ie * 4];
            float hvv[4] = {hv.x, hv.y, hv.z, hv.w};
            float wvv[4] = {wv.x, wv.y, wv.z, wv.w};
            #pragma unroll
            for (int i = 0; i < 4; i++)
                #pragma unroll
                for (int j = 0; j < 4; j++)
                    acc[i][j] += hvv[i] * wvv[j];
        }
        __syncthreads();
    }

    #pragma unroll
    for (int i = 0; i < 4; i++) {
        f4 v = make_float4(acc[i][0], acc[i][1], acc[i][2], acc[i][3]);
        *(f4*)&part[((size_t)z * BB + b0 + ib * 4 + i) * DD + e0 + ie * 4] = v;
    }
}

// ---------------------------------------------------------------------------
// Kernel B: fused masked-softmax attention + concat copy. One block per b.
// 1024 threads = 4 groups x 256; group g handles t in [g*64, g*64+64) with an
// independent online softmax; merged flash-style at the end.
// Each thread owns channels [8*tl, 8*tl+8). Single HBM pass over prev_h_dec.
// ---------------------------------------------------------------------------
__global__ __launch_bounds__(1024) void attn_fused(
    const float* __restrict__ h_dec,   // [B][D]
    const float* __restrict__ prev,    // [B][TC][D]
    const unsigned char* __restrict__ maskb,
    const float* __restrict__ part,    // [4][B][D] hw partials
    float* __restrict__ out)           // [B*D ctx | B*(TC+1)*D new_prev]
{
    __shared__ float hw[DD];           // hw row; reused as ctx at the end
    __shared__ float wred[2][16];
    __shared__ float gm[4], gl[4];

    const int b   = blockIdx.x;
    const int tid = threadIdx.x;

    // reduce the 4 split-K partials -> hw row in LDS
    for (int k = tid; k < DD; k += 1024) {
        hw[k] = part[(size_t)b * DD + k]
              + part[((size_t)BB + b) * DD + k]
              + part[((size_t)2 * BB + b) * DD + k]
              + part[((size_t)3 * BB + b) * DD + k];
    }

    // mask dtype-layout detection: bool bytes -> nonzero bytes at k%4!=0
    int nz = 0;
    #pragma unroll
    for (int k = 1; k < 64; k++)
        if ((k & 3) != 0) nz += (maskb[k] != 0);
    const bool boolLayout = (nz > 0);
    const int* maski = (const int*)maskb;

    __syncthreads();

    const int g    = tid >> 8;       // group 0..3
    const int tl   = tid & 255;      // thread-in-group
    const int wv   = tid >> 6;       // wave 0..15
    const int lane = tid & 63;

    float hwr[8];
    #pragma unroll
    for (int j = 0; j < 8; j++) hwr[j] = hw[tl * 8 + j];

    float m = -INFINITY, l = 0.f;
    float acc[8] = {0.f, 0.f, 0.f, 0.f, 0.f, 0.f, 0.f, 0.f};

    const float* pb = prev + (size_t)b * TCC * DD + tl * 8;
    float* cp = out + (size_t)BB * DD + (size_t)b * (TCC + 1) * DD + tl * 8;

    f4 c0 = *(const f4*)(pb + (size_t)(g * 64) * DD);
    f4 c1 = *(const f4*)(pb + (size_t)(g * 64) * DD + 4);

    for (int i = 0; i < 64; i++) {
        const int t = g * 64 + i;
        f4 n0 = c0, n1 = c1;
        if (i < 63) {
            n0 = *(const f4*)(pb + (size_t)(t + 1) * DD);
            n1 = *(const f4*)(pb + (size_t)(t + 1) * DD + 4);
        }
        // fused copy into new_prev
        *(f4*)(cp + (size_t)t * DD)     = c0;
        *(f4*)(cp + (size_t)t * DD + 4) = c1;
        // partial dot with hw row (registers)
        float p = c0.x * hwr[0] + c0.y * hwr[1] + c0.z * hwr[2] + c0.w * hwr[3]
                + c1.x * hwr[4] + c1.y * hwr[5] + c1.z * hwr[6] + c1.w * hwr[7];
        #pragma unroll
        for (int off = 32; off; off >>= 1) p += __shfl_xor(p, off, 64);
        if (lane == 0) wred[i & 1][wv] = p;
        __syncthreads();
        const float e = wred[i & 1][4 * g] + wred[i & 1][4 * g + 1]
                      + wred[i & 1][4 * g + 2] + wred[i & 1][4 * g + 3];
        const bool mk = boolLayout ? (maskb[(size_t)b * TCC + t] != 0)
                                   : (maski[(size_t)b * TCC + t] != 0);
        if (mk) {
            if (e > m) {
                const float sc = __expf(m - e);   // m=-inf first time -> 0
                l *= sc;
                #pragma unroll
                for (int j = 0; j < 8; j++) acc[j] *= sc;
                m = e;
            }
            const float w = __expf(e - m);
            l += w;
            acc[0] += w * c0.x; acc[1] += w * c0.y;
            acc[2] += w * c0.z; acc[3] += w * c0.w;
            acc[4] += w * c1.x; acc[5] += w * c1.y;
            acc[6] += w * c1.z; acc[7] += w * c1.w;
        }
        c0 = n0; c1 = n1;
    }

    // merge the 4 groups (flash-style)
    __syncthreads();
    if (tl == 0) { gm[g] = m; gl[g] = l; }
    __syncthreads();
    const float mstar = fmaxf(fmaxf(gm[0], gm[1]), fmaxf(gm[2], gm[3]));
    float L = 0.f;
    #pragma unroll
    for (int q = 0; q < 4; q++) L += gl[q] * __expf(gm[q] - mstar);
    const float f = __expf(gm[g] - mstar);

    for (int ph = 0; ph < 4; ph++) {
        if (g == ph) {
            #pragma unroll
            for (int j = 0; j < 8; j++) {
                if (ph == 0) hw[tl * 8 + j]  = f * acc[j];
                else         hw[tl * 8 + j] += f * acc[j];
            }
        }
        __syncthreads();
    }

    const float invL = 1.0f / L;
    for (int k = tid; k < DD; k += 1024)
        out[(size_t)b * DD + k] = hw[k] * invL;
    // append h_dec as row TC of new_prev
    for (int k = tid; k < DD; k += 1024)
        out[(size_t)BB * DD + ((size_t)b * (TCC + 1) + TCC) * DD + k] =
            h_dec[(size_t)b * DD + k];
}

extern "C" void kernel_launch(void* const* d_in, const int* in_sizes, int n_in,
                              void* d_out, int out_size, void* d_ws, size_t ws_size,
                              hipStream_t stream) {
    const float* h_dec = (const float*)d_in[0];
    const float* prev  = (const float*)d_in[1];
    const unsigned char* maskb = (const unsigned char*)d_in[2];
    const float* W = (const float*)d_in[3];
    float* out  = (float*)d_out;
    float* part = (float*)d_ws;   // 4 * B * D * 4 = 8 MB of scratch

    hipLaunchKernelGGL(hw_gemm_partial, dim3(32, 4, 4), dim3(256), 0, stream,
                       h_dec, W, part);
    hipLaunchKernelGGL(attn_fused, dim3(BB), dim3(1024), 0, stream,
                       h_dec, prev, maskb, part, out);
}